// Round 3
// baseline (506.641 us; speedup 1.0000x reference)
//
#include <hip/hip_runtime.h>
#include <stdint.h>

// ConvAttnLayer: B=16, L=512, J=4, O=4, D=E=64.
// out0 = mean_j softmax(X_j W_oj X_j^T / 8) X_j ; out1 = attn (268 MB fp32).
//
// Round-4: occupancy 8 -> 16 waves/CU + serial-chain trims.
//  - j-split: 512 blocks x 512 thr; block handles j in {2jh, 2jh+1}. Staging is
//    per-(block,j) so no duplicated work; out0 combined via memset + 2-way
//    unsafeAtomicAdd (f32, ~1e-7 rounding vs 3e-3 tolerance).
//  - LDS 76KB (XB 64K + WT 8K + QB 8x512B) -> 2 blocks/CU at 512 thr = 16 waves/CU.
//    QB shrunk via 4 quarter-bounces (one 16x16 e-tile per h; lane's bq0 needs
//    e = g*8..+7 => comes from h = g>>1 round, e_local = (g&1)*8+i).
//  - P3 attn + epilogue stores go DIRECT from MFMA regs (lane holds 4 consecutive
//    m resp. d for one l): address-set identical to the old LDS bounce, so same
//    coalescing, minus ~640 LDS ops + lgkm chains per wave*j.
//  - nt hint dropped on attn stores (suspect: partial-line writeback + write-
//    allocate refetch caused FETCH=100MB on an 8MB input and 1.56x write amp).

typedef __bf16 bf16x8 __attribute__((ext_vector_type(8)));
typedef float  f32x4  __attribute__((ext_vector_type(4)));
typedef unsigned int u32;
typedef u32 u32x4 __attribute__((ext_vector_type(4)));

#define XB_OFF  0         // 65536: X bf16 — XRM (row-major, swizzled) during
                          //        Q/S phase, then XCM (col-major) during P3
#define WT_OFF  65536     // 8192 : W^T [e][d], stride 128, cell XOR (d>>3)^(e&7)
#define QB_OFF  73728     // 8*512: per-wave Q quarter-bounce (16 rows x 32B)
#define LDS_BYTES 77824

static __device__ __forceinline__ u32 f2bf(float f) {
    u32 u = __builtin_bit_cast(u32, f);
    u += 0x7fffu + ((u >> 16) & 1u);   // RNE (finite)
    return u >> 16;
}
static __device__ __forceinline__ float bflo2f(u32 p) { return __builtin_bit_cast(float, p << 16); }
static __device__ __forceinline__ float bfhi2f(u32 p) { return __builtin_bit_cast(float, p & 0xffff0000u); }

__global__ __launch_bounds__(512, 4) void convattn_kernel(
    const float* __restrict__ inp,   // [16,512,4,64]
    const float* __restrict__ Wg,    // [4,4,64,64]
    float* __restrict__ out)         // out0 (2097152, pre-zeroed) ++ attn (67108864)
{
    extern __shared__ __align__(16) char smem[];
    const int tid  = threadIdx.x;
    const int wave = tid >> 6;
    const int lane = tid & 63;
    const int g    = lane >> 4;     // MFMA k-group
    const int ln   = lane & 15;     // MFMA row/col within tile

    const int bid = blockIdx.x;
    const int b  = bid & 15;        // bid%8 = b%8: same-b blocks share an XCD
    const int o  = (bid >> 4) & 3;
    const int lt = (bid >> 6) & 3;  // 0..3: 128 l's per block
    const int jh = bid >> 8;        // 0..1: j in {2jh, 2jh+1}
    const int l0 = lt * 128 + wave * 16;   // this wave's 16 l-columns

    float* attn_out = out + (size_t)2097152;
    char* qb = smem + QB_OFF + wave * 512;   // wave-private Q quarter-bounce

    const int sq = tid & 15;   // staging e-quad (e0 = sq*4)
    const int sp = tid >> 4;   // 0..31

    f32x4 acc_c[4];
    #pragma unroll
    for (int i = 0; i < 4; ++i) { f32x4 z = {0.f,0.f,0.f,0.f}; acc_c[i] = z; }

    #pragma unroll 1
    for (int jj = 0; jj < 2; ++jj) {
        const int j = jh * 2 + jj;
        __syncthreads();   // guard XB/WT reuse across j

        // ---------------- stage XRM (X row-major bf16, swizzled) + W^T ----------------
        {
            const int e0 = sq << 2;
            #pragma unroll
            for (int it = 0; it < 8; ++it) {
                const int m0 = it * 64 + sp * 2;
                const float* src = inp + (((size_t)b * 512 + m0) * 4 + j) * 64 + e0;
                const float4 va = *(const float4*)src;
                const float4 vb = *(const float4*)(src + 256);   // row m0+1
                uint2 w0; w0.x = f2bf(va.x) | (f2bf(va.y) << 16); w0.y = f2bf(va.z) | (f2bf(va.w) << 16);
                *(uint2*)(smem + XB_OFF + m0 * 128 + (((sq >> 1) ^ (m0 & 7)) * 16) + ((sq & 1) * 8)) = w0;
                uint2 w1; w1.x = f2bf(vb.x) | (f2bf(vb.y) << 16); w1.y = f2bf(vb.z) | (f2bf(vb.w) << 16);
                *(uint2*)(smem + XB_OFF + (m0 + 1) * 128 + (((sq >> 1) ^ ((m0 + 1) & 7)) * 16) + ((sq & 1) * 8)) = w1;
            }
            // W^T: thread -> W row d = tid>>3, e-range (tid&7)*8 .. +7
            const int wd = tid >> 3;
            const int we = (tid & 7) << 3;
            const float* wsrc = Wg + (((size_t)o * 4 + j) * 64 + wd) * 64 + we;
            #pragma unroll
            for (int c = 0; c < 2; ++c) {
                const float4 wv = *(const float4*)(wsrc + c * 4);
                const int e = we + c * 4;
                const u32 q0 = f2bf(wv.x), q1 = f2bf(wv.y), q2 = f2bf(wv.z), q3 = f2bf(wv.w);
                *(unsigned short*)(smem + WT_OFF + (e + 0) * 128 + (((wd >> 3) ^ ((e + 0) & 7)) * 16) + ((wd & 7) * 2)) = (unsigned short)q0;
                *(unsigned short*)(smem + WT_OFF + (e + 1) * 128 + (((wd >> 3) ^ ((e + 1) & 7)) * 16) + ((wd & 7) * 2)) = (unsigned short)q1;
                *(unsigned short*)(smem + WT_OFF + (e + 2) * 128 + (((wd >> 3) ^ ((e + 2) & 7)) * 16) + ((wd & 7) * 2)) = (unsigned short)q2;
                *(unsigned short*)(smem + WT_OFF + (e + 3) * 128 + (((wd >> 3) ^ ((e + 3) & 7)) * 16) + ((wd & 7) * 2)) = (unsigned short)q3;
            }
        }
        __syncthreads();

        // ---------------- Q for this wave's 16 l's; 4 quarter-bounces -> Q^T B-frags ----------------
        bf16x8 bq0, bq1;
        {
            const int lq = l0 + ln;
            const bf16x8 aq0 = *(const bf16x8*)(smem + XB_OFF + lq * 128 + ((g ^ (lq & 7)) * 16));
            const bf16x8 aq1 = *(const bf16x8*)(smem + XB_OFF + lq * 128 + (((4 + g) ^ (lq & 7)) * 16));
            bf16x8 rd[4];
            #pragma unroll
            for (int h = 0; h < 4; ++h) {
                const int e = h * 16 + ln;
                const bf16x8 bw0 = *(const bf16x8*)(smem + WT_OFF + e * 128 + ((g ^ (e & 7)) * 16));
                const bf16x8 bw1 = *(const bf16x8*)(smem + WT_OFF + e * 128 + (((4 + g) ^ (e & 7)) * 16));
                f32x4 t = {0.f,0.f,0.f,0.f};
                t = __builtin_amdgcn_mfma_f32_16x16x32_bf16(aq0, bw0, t, 0, 0, 0);
                t = __builtin_amdgcn_mfma_f32_16x16x32_bf16(aq1, bw1, t, 0, 0, 0);
                // bounce tile: row = l_local = g*4+r, col = e_local = ln (16 rows x 32B)
                #pragma unroll
                for (int r = 0; r < 4; ++r)
                    *(unsigned short*)(qb + (g * 4 + r) * 32 + ln * 2) = (unsigned short)f2bf(t[r]);
                rd[h] = *(const bf16x8*)(qb + ln * 32 + (g & 1) * 16);
                __builtin_amdgcn_sched_barrier(0);  // keep next h's writes after this read
            }
            bq0 = (g < 2) ? rd[0] : rd[1];   // lane's bq0 = e g*8..+7 -> h = g>>1
            bq1 = (g < 2) ? rd[2] : rd[3];
        }

        // ---------------- S phase: S^T = X * Q^T, exp (no max pass), stash bf16 E ----------------
        float sum = 0.f;
        u32 sLo[32], sHi[32];
        #pragma unroll
        for (int mt = 0; mt < 32; ++mt) {
            const int m = mt * 16 + ln;
            const bf16x8 ax0 = *(const bf16x8*)(smem + XB_OFF + m * 128 + ((g ^ (m & 7)) * 16));
            const bf16x8 ax1 = *(const bf16x8*)(smem + XB_OFF + m * 128 + (((4 + g) ^ (m & 7)) * 16));
            f32x4 t = {0.f,0.f,0.f,0.f};
            t = __builtin_amdgcn_mfma_f32_16x16x32_bf16(ax0, bq0, t, 0, 0, 0);
            t = __builtin_amdgcn_mfma_f32_16x16x32_bf16(ax1, bq1, t, 0, 0, 0);
            const float e0v = __expf(t[0] * 0.125f);   // |S/8| <= ~6.5: fp32-safe
            const float e1v = __expf(t[1] * 0.125f);
            const float e2v = __expf(t[2] * 0.125f);
            const float e3v = __expf(t[3] * 0.125f);
            sum += (e0v + e1v) + (e2v + e3v);
            sLo[mt] = f2bf(e0v) | (f2bf(e1v) << 16);
            sHi[mt] = f2bf(e2v) | (f2bf(e3v) << 16);
        }
        sum += __shfl_xor(sum, 16, 64);
        sum += __shfl_xor(sum, 32, 64);
        const float inv = 1.0f / sum;

        __syncthreads();   // all waves done reading XRM

        // ---------------- restage XB as XCM (X col-major bf16, swizzled; L2-hot) ----------------
        {
            const int e0 = sq << 2;
            #pragma unroll
            for (int it = 0; it < 8; ++it) {
                const int m0 = it * 64 + sp * 2;
                const float* src = inp + (((size_t)b * 512 + m0) * 4 + j) * 64 + e0;
                const float4 va = *(const float4*)src;
                const float4 vb = *(const float4*)(src + 256);
                const u32 p0 = f2bf(va.x) | (f2bf(vb.x) << 16);
                const u32 p1 = f2bf(va.y) | (f2bf(vb.y) << 16);
                const u32 p2 = f2bf(va.z) | (f2bf(vb.z) << 16);
                const u32 p3v = f2bf(va.w) | (f2bf(vb.w) << 16);
                const u32 pc[4] = {p0, p1, p2, p3v};
                #pragma unroll
                for (int c = 0; c < 4; ++c) {
                    const int d = e0 + c;
                    *(u32*)(smem + XB_OFF + d * 1024 + (((m0 >> 3) ^ ((d >> 2) & 7)) * 16) + ((m0 & 7) * 2)) = pc[c];
                }
            }
        }
        __syncthreads();

        // ---------------- P3: direct attn stores + ctx^T += X^T * E^T ----------------
        // Lane (ln,g) holds E^T[m = mt*16+g*4+r][l = l0+ln]: 4 consecutive m for one l
        // -> direct f32x4 store; address set identical to the old LDS bounce.
        const size_t abase = ((size_t)((o * 4 + j) * 16 + b)) * 262144 + (size_t)(l0 + ln) * 512;
        const int srcLo = ((g & 1) << 5) + ln;
        const int srcHi = srcLo + 16;
        #pragma unroll
        for (int ch = 0; ch < 16; ++ch) {
            u32 pLo[2], pHi[2];
            #pragma unroll
            for (int s = 0; s < 2; ++s) {
                const int mt = ch * 2 + s;
                const float a0v = bflo2f(sLo[mt]) * inv;
                const float a1v = bfhi2f(sLo[mt]) * inv;
                const float a2v = bflo2f(sHi[mt]) * inv;
                const float a3v = bfhi2f(sHi[mt]) * inv;
                const f32x4 av = {a0v, a1v, a2v, a3v};
                *(f32x4*)(attn_out + abase + mt * 16 + g * 4) = av;
                pLo[s] = f2bf(a0v) | (f2bf(a1v) << 16);
                pHi[s] = f2bf(a2v) | (f2bf(a3v) << 16);
            }
            // E^T B-frag via cross-lane (g-only moves: same column stays in same ln)
            const u32 a0s = (u32)__shfl((int)pLo[0], srcLo, 64);
            const u32 a1s = (u32)__shfl((int)pHi[0], srcLo, 64);
            const u32 a2s = (u32)__shfl((int)pLo[0], srcHi, 64);
            const u32 a3s = (u32)__shfl((int)pHi[0], srcHi, 64);
            const u32 b0s = (u32)__shfl((int)pLo[1], srcLo, 64);
            const u32 b1s = (u32)__shfl((int)pHi[1], srcLo, 64);
            const u32 b2s = (u32)__shfl((int)pLo[1], srcHi, 64);
            const u32 b3s = (u32)__shfl((int)pHi[1], srcHi, 64);
            const bool hi = (g >= 2);
            const u32 dw0 = hi ? b0s : a0s;
            const u32 dw1 = hi ? b1s : a1s;
            const u32 dw2 = hi ? b2s : a2s;
            const u32 dw3 = hi ? b3s : a3s;
            const bf16x8 bfrag = __builtin_bit_cast(bf16x8, (u32x4){dw0, dw1, dw2, dw3});
            #pragma unroll
            for (int dt = 0; dt < 4; ++dt) {
                const int d = dt * 16 + ln;
                const bf16x8 ax = *(const bf16x8*)(smem + XB_OFF + d * 1024 +
                                   (((ch * 4 + g) ^ ((d >> 2) & 7)) * 16));
                acc_c[dt] = __builtin_amdgcn_mfma_f32_16x16x32_bf16(ax, bfrag, acc_c[dt], 0, 0, 0);
            }
        }
    }

    // ---------------- epilogue: out[b,l,o,d] += 0.25 * ctx_partial (2-way j-split) ----------------
    // Lane (ln,g) holds ctx^T[d = dt*16+g*4+r][l = l0+ln]: 4 consecutive d for one l.
    float* obase = out + (((size_t)b * 512 + (l0 + ln)) * 4 + o) * 64;
    #pragma unroll
    for (int dt = 0; dt < 4; ++dt) {
        #pragma unroll
        for (int r = 0; r < 4; ++r)
            unsafeAtomicAdd(obase + dt * 16 + g * 4 + r, acc_c[dt][r] * 0.25f);
    }
}

extern "C" void kernel_launch(void* const* d_in, const int* in_sizes, int n_in,
                              void* d_out, int out_size, void* d_ws, size_t ws_size,
                              hipStream_t stream) {
    const float* inp = (const float*)d_in[0];
    const float* Wg  = (const float*)d_in[1];
    float* out = (float*)d_out;
    (void)hipMemsetAsync(d_out, 0, (size_t)2097152 * sizeof(float), stream);  // out0 only
    (void)hipFuncSetAttribute((const void*)convattn_kernel,
                              hipFuncAttributeMaxDynamicSharedMemorySize, LDS_BYTES);
    convattn_kernel<<<dim3(512), dim3(512), LDS_BYTES, stream>>>(inp, Wg, out);
}

// Round 4
// 441.194 us; speedup vs baseline: 1.1483x; 1.1483x over previous
//
#include <hip/hip_runtime.h>
#include <stdint.h>

// ConvAttnLayer: B=16, L=512, J=4, O=4, D=E=64.
// out0 = mean_j softmax(X_j W_oj X_j^T / 8) X_j ; out1 = attn (268 MB fp32).
//
// Round-5: round-4 structure with the VGPR budget pinned.
//  Round-4 post-mortem: __launch_bounds__(512,4) made hipcc squeeze to
//  VGPR=64 (one tier past the bound) -> sLo/sHi stash spilled to scratch
//  (+134 MB each way, dur 192->284). Fix: amdgpu_waves_per_eu(4,4) pins
//  exactly 4 waves/EU -> hard VGPR budget 128 (fits: round-0 allocated
//  exactly 128 for a strictly larger live set), no incentive to squeeze.
//  - j-split: 512 blocks x 512 thr; block handles j in {2jh, 2jh+1}; out0
//    combined via memset + 2-way unsafeAtomicAdd.
//  - LDS 76KB (XB 64K + WT 8K + QB 8x512B) -> 2 blocks/CU = 16 waves/CU.
//  - P3 attn + epilogue stores direct from MFMA regs; nt hint restored on
//    attn (write-once stream; keep it out of L2 so X panels stay resident).

typedef __bf16 bf16x8 __attribute__((ext_vector_type(8)));
typedef float  f32x4  __attribute__((ext_vector_type(4)));
typedef unsigned int u32;
typedef u32 u32x4 __attribute__((ext_vector_type(4)));

#define XB_OFF  0         // 65536: X bf16 — XRM (row-major, swizzled) during
                          //        Q/S phase, then XCM (col-major) during P3
#define WT_OFF  65536     // 8192 : W^T [e][d], stride 128, cell XOR (d>>3)^(e&7)
#define QB_OFF  73728     // 8*512: per-wave Q quarter-bounce (16 rows x 32B)
#define LDS_BYTES 77824

static __device__ __forceinline__ u32 f2bf(float f) {
    u32 u = __builtin_bit_cast(u32, f);
    u += 0x7fffu + ((u >> 16) & 1u);   // RNE (finite)
    return u >> 16;
}
static __device__ __forceinline__ float bflo2f(u32 p) { return __builtin_bit_cast(float, p << 16); }
static __device__ __forceinline__ float bfhi2f(u32 p) { return __builtin_bit_cast(float, p & 0xffff0000u); }

__global__ void __launch_bounds__(512)
__attribute__((amdgpu_waves_per_eu(4, 4)))
convattn_kernel(
    const float* __restrict__ inp,   // [16,512,4,64]
    const float* __restrict__ Wg,    // [4,4,64,64]
    float* __restrict__ out)         // out0 (2097152, pre-zeroed) ++ attn (67108864)
{
    extern __shared__ __align__(16) char smem[];
    const int tid  = threadIdx.x;
    const int wave = tid >> 6;
    const int lane = tid & 63;
    const int g    = lane >> 4;     // MFMA k-group
    const int ln   = lane & 15;     // MFMA row/col within tile

    const int bid = blockIdx.x;
    const int b  = bid & 15;        // bid%8 = b%8: same-b blocks share an XCD
    const int o  = (bid >> 4) & 3;
    const int lt = (bid >> 6) & 3;  // 0..3: 128 l's per block
    const int jh = bid >> 8;        // 0..1: j in {2jh, 2jh+1}
    const int l0 = lt * 128 + wave * 16;   // this wave's 16 l-columns

    float* attn_out = out + (size_t)2097152;
    char* qb = smem + QB_OFF + wave * 512;   // wave-private Q quarter-bounce

    const int sq = tid & 15;   // staging e-quad (e0 = sq*4)
    const int sp = tid >> 4;   // 0..31

    f32x4 acc_c[4];
    #pragma unroll
    for (int i = 0; i < 4; ++i) { f32x4 z = {0.f,0.f,0.f,0.f}; acc_c[i] = z; }

    #pragma unroll 1
    for (int jj = 0; jj < 2; ++jj) {
        const int j = jh * 2 + jj;
        __syncthreads();   // guard XB/WT reuse across j

        // ---------------- stage XRM (X row-major bf16, swizzled) + W^T ----------------
        {
            const int e0 = sq << 2;
            #pragma unroll
            for (int it = 0; it < 8; ++it) {
                const int m0 = it * 64 + sp * 2;
                const float* src = inp + (((size_t)b * 512 + m0) * 4 + j) * 64 + e0;
                const float4 va = *(const float4*)src;
                const float4 vb = *(const float4*)(src + 256);   // row m0+1
                uint2 w0; w0.x = f2bf(va.x) | (f2bf(va.y) << 16); w0.y = f2bf(va.z) | (f2bf(va.w) << 16);
                *(uint2*)(smem + XB_OFF + m0 * 128 + (((sq >> 1) ^ (m0 & 7)) * 16) + ((sq & 1) * 8)) = w0;
                uint2 w1; w1.x = f2bf(vb.x) | (f2bf(vb.y) << 16); w1.y = f2bf(vb.z) | (f2bf(vb.w) << 16);
                *(uint2*)(smem + XB_OFF + (m0 + 1) * 128 + (((sq >> 1) ^ ((m0 + 1) & 7)) * 16) + ((sq & 1) * 8)) = w1;
            }
            // W^T: thread -> W row d = tid>>3, e-range (tid&7)*8 .. +7
            const int wd = tid >> 3;
            const int we = (tid & 7) << 3;
            const float* wsrc = Wg + (((size_t)o * 4 + j) * 64 + wd) * 64 + we;
            #pragma unroll
            for (int c = 0; c < 2; ++c) {
                const float4 wv = *(const float4*)(wsrc + c * 4);
                const int e = we + c * 4;
                const u32 q0 = f2bf(wv.x), q1 = f2bf(wv.y), q2 = f2bf(wv.z), q3 = f2bf(wv.w);
                *(unsigned short*)(smem + WT_OFF + (e + 0) * 128 + (((wd >> 3) ^ ((e + 0) & 7)) * 16) + ((wd & 7) * 2)) = (unsigned short)q0;
                *(unsigned short*)(smem + WT_OFF + (e + 1) * 128 + (((wd >> 3) ^ ((e + 1) & 7)) * 16) + ((wd & 7) * 2)) = (unsigned short)q1;
                *(unsigned short*)(smem + WT_OFF + (e + 2) * 128 + (((wd >> 3) ^ ((e + 2) & 7)) * 16) + ((wd & 7) * 2)) = (unsigned short)q2;
                *(unsigned short*)(smem + WT_OFF + (e + 3) * 128 + (((wd >> 3) ^ ((e + 3) & 7)) * 16) + ((wd & 7) * 2)) = (unsigned short)q3;
            }
        }
        __syncthreads();

        // ---------------- Q for this wave's 16 l's; 4 quarter-bounces -> Q^T B-frags ----------------
        bf16x8 bq0, bq1;
        {
            const int lq = l0 + ln;
            const bf16x8 aq0 = *(const bf16x8*)(smem + XB_OFF + lq * 128 + ((g ^ (lq & 7)) * 16));
            const bf16x8 aq1 = *(const bf16x8*)(smem + XB_OFF + lq * 128 + (((4 + g) ^ (lq & 7)) * 16));
            bf16x8 rd[4];
            #pragma unroll
            for (int h = 0; h < 4; ++h) {
                const int e = h * 16 + ln;
                const bf16x8 bw0 = *(const bf16x8*)(smem + WT_OFF + e * 128 + ((g ^ (e & 7)) * 16));
                const bf16x8 bw1 = *(const bf16x8*)(smem + WT_OFF + e * 128 + (((4 + g) ^ (e & 7)) * 16));
                f32x4 t = {0.f,0.f,0.f,0.f};
                t = __builtin_amdgcn_mfma_f32_16x16x32_bf16(aq0, bw0, t, 0, 0, 0);
                t = __builtin_amdgcn_mfma_f32_16x16x32_bf16(aq1, bw1, t, 0, 0, 0);
                // bounce tile: row = l_local = g*4+r, col = e_local = ln (16 rows x 32B)
                #pragma unroll
                for (int r = 0; r < 4; ++r)
                    *(unsigned short*)(qb + (g * 4 + r) * 32 + ln * 2) = (unsigned short)f2bf(t[r]);
                rd[h] = *(const bf16x8*)(qb + ln * 32 + (g & 1) * 16);
                __builtin_amdgcn_sched_barrier(0);  // keep next h's writes after this read
            }
            bq0 = (g < 2) ? rd[0] : rd[1];   // lane's bq0 = e g*8..+7 -> h = g>>1
            bq1 = (g < 2) ? rd[2] : rd[3];
        }

        // ---------------- S phase: S^T = X * Q^T, exp (no max pass), stash bf16 E ----------------
        float sum = 0.f;
        u32 sLo[32], sHi[32];
        #pragma unroll
        for (int mt = 0; mt < 32; ++mt) {
            const int m = mt * 16 + ln;
            const bf16x8 ax0 = *(const bf16x8*)(smem + XB_OFF + m * 128 + ((g ^ (m & 7)) * 16));
            const bf16x8 ax1 = *(const bf16x8*)(smem + XB_OFF + m * 128 + (((4 + g) ^ (m & 7)) * 16));
            f32x4 t = {0.f,0.f,0.f,0.f};
            t = __builtin_amdgcn_mfma_f32_16x16x32_bf16(ax0, bq0, t, 0, 0, 0);
            t = __builtin_amdgcn_mfma_f32_16x16x32_bf16(ax1, bq1, t, 0, 0, 0);
            const float e0v = __expf(t[0] * 0.125f);   // |S/8| <= ~6.5: fp32-safe
            const float e1v = __expf(t[1] * 0.125f);
            const float e2v = __expf(t[2] * 0.125f);
            const float e3v = __expf(t[3] * 0.125f);
            sum += (e0v + e1v) + (e2v + e3v);
            sLo[mt] = f2bf(e0v) | (f2bf(e1v) << 16);
            sHi[mt] = f2bf(e2v) | (f2bf(e3v) << 16);
        }
        sum += __shfl_xor(sum, 16, 64);
        sum += __shfl_xor(sum, 32, 64);
        const float inv = 1.0f / sum;

        __syncthreads();   // all waves done reading XRM

        // ---------------- restage XB as XCM (X col-major bf16, swizzled; L2-hot) ----------------
        {
            const int e0 = sq << 2;
            #pragma unroll
            for (int it = 0; it < 8; ++it) {
                const int m0 = it * 64 + sp * 2;
                const float* src = inp + (((size_t)b * 512 + m0) * 4 + j) * 64 + e0;
                const float4 va = *(const float4*)src;
                const float4 vb = *(const float4*)(src + 256);
                const u32 p0 = f2bf(va.x) | (f2bf(vb.x) << 16);
                const u32 p1 = f2bf(va.y) | (f2bf(vb.y) << 16);
                const u32 p2 = f2bf(va.z) | (f2bf(vb.z) << 16);
                const u32 p3v = f2bf(va.w) | (f2bf(vb.w) << 16);
                const u32 pc[4] = {p0, p1, p2, p3v};
                #pragma unroll
                for (int c = 0; c < 4; ++c) {
                    const int d = e0 + c;
                    *(u32*)(smem + XB_OFF + d * 1024 + (((m0 >> 3) ^ ((d >> 2) & 7)) * 16) + ((m0 & 7) * 2)) = pc[c];
                }
            }
        }
        __syncthreads();

        // ---------------- P3: direct attn stores + ctx^T += X^T * E^T ----------------
        // Lane (ln,g) holds E^T[m = mt*16+g*4+r][l = l0+ln]: 4 consecutive m for one l
        // -> direct f32x4 store; address set identical to the old LDS bounce.
        const size_t abase = ((size_t)((o * 4 + j) * 16 + b)) * 262144 + (size_t)(l0 + ln) * 512;
        const int srcLo = ((g & 1) << 5) + ln;
        const int srcHi = srcLo + 16;
        #pragma unroll
        for (int ch = 0; ch < 16; ++ch) {
            u32 pLo[2], pHi[2];
            #pragma unroll
            for (int s = 0; s < 2; ++s) {
                const int mt = ch * 2 + s;
                const float a0v = bflo2f(sLo[mt]) * inv;
                const float a1v = bfhi2f(sLo[mt]) * inv;
                const float a2v = bflo2f(sHi[mt]) * inv;
                const float a3v = bfhi2f(sHi[mt]) * inv;
                const f32x4 av = {a0v, a1v, a2v, a3v};
                __builtin_nontemporal_store(av,
                    (f32x4*)(attn_out + abase + mt * 16 + g * 4));
                pLo[s] = f2bf(a0v) | (f2bf(a1v) << 16);
                pHi[s] = f2bf(a2v) | (f2bf(a3v) << 16);
            }
            // E^T B-frag via cross-lane (g-only moves: same column stays in same ln)
            const u32 a0s = (u32)__shfl((int)pLo[0], srcLo, 64);
            const u32 a1s = (u32)__shfl((int)pHi[0], srcLo, 64);
            const u32 a2s = (u32)__shfl((int)pLo[0], srcHi, 64);
            const u32 a3s = (u32)__shfl((int)pHi[0], srcHi, 64);
            const u32 b0s = (u32)__shfl((int)pLo[1], srcLo, 64);
            const u32 b1s = (u32)__shfl((int)pHi[1], srcLo, 64);
            const u32 b2s = (u32)__shfl((int)pLo[1], srcHi, 64);
            const u32 b3s = (u32)__shfl((int)pHi[1], srcHi, 64);
            const bool hi = (g >= 2);
            const u32 dw0 = hi ? b0s : a0s;
            const u32 dw1 = hi ? b1s : a1s;
            const u32 dw2 = hi ? b2s : a2s;
            const u32 dw3 = hi ? b3s : a3s;
            const bf16x8 bfrag = __builtin_bit_cast(bf16x8, (u32x4){dw0, dw1, dw2, dw3});
            #pragma unroll
            for (int dt = 0; dt < 4; ++dt) {
                const int d = dt * 16 + ln;
                const bf16x8 ax = *(const bf16x8*)(smem + XB_OFF + d * 1024 +
                                   (((ch * 4 + g) ^ ((d >> 2) & 7)) * 16));
                acc_c[dt] = __builtin_amdgcn_mfma_f32_16x16x32_bf16(ax, bfrag, acc_c[dt], 0, 0, 0);
            }
        }
    }

    // ---------------- epilogue: out[b,l,o,d] += 0.25 * ctx_partial (2-way j-split) ----------------
    // Lane (ln,g) holds ctx^T[d = dt*16+g*4+r][l = l0+ln]: 4 consecutive d for one l.
    float* obase = out + (((size_t)b * 512 + (l0 + ln)) * 4 + o) * 64;
    #pragma unroll
    for (int dt = 0; dt < 4; ++dt) {
        #pragma unroll
        for (int r = 0; r < 4; ++r)
            unsafeAtomicAdd(obase + dt * 16 + g * 4 + r, acc_c[dt][r] * 0.25f);
    }
}

extern "C" void kernel_launch(void* const* d_in, const int* in_sizes, int n_in,
                              void* d_out, int out_size, void* d_ws, size_t ws_size,
                              hipStream_t stream) {
    const float* inp = (const float*)d_in[0];
    const float* Wg  = (const float*)d_in[1];
    float* out = (float*)d_out;
    (void)hipMemsetAsync(d_out, 0, (size_t)2097152 * sizeof(float), stream);  // out0 only
    (void)hipFuncSetAttribute((const void*)convattn_kernel,
                              hipFuncAttributeMaxDynamicSharedMemorySize, LDS_BYTES);
    convattn_kernel<<<dim3(512), dim3(512), LDS_BYTES, stream>>>(inp, Wg, out);
}

// Round 5
// 393.718 us; speedup vs baseline: 1.2868x; 1.1206x over previous
//
#include <hip/hip_runtime.h>
#include <stdint.h>

// ConvAttnLayer: B=16, L=512, J=4, O=4, D=E=64.
// out0 = mean_j softmax(X_j W_oj X_j^T / 8) X_j ; out1 = attn (268 MB fp32).
//
// Round-6: round-4 structure, register tier fixed.
//  History: lb(512,4) -> VGPR=64 + scratch spill of the 64-reg E-stash
//  (dur 284); waves_per_eu(4,4) did NOT bind (VGPR still 64, dur 229).
//  The only settings that ever gave VGPR=128 spill-free are lb(*,2):
//  round-0 (512 thr, larger live set) and round-2 (256 thr). So: exactly
//  one change vs round-4 — __launch_bounds__(512, 2). Compiler lands at
//  128 VGPR -> 4 waves/EU -> 2 blocks/CU (LDS 2x76KB=152KB<160KB) =
//  16 waves/CU, no scratch.
//  - j-split: 512 blocks x 512 thr; block handles j in {2jh, 2jh+1}; out0
//    combined via memset + 2-way unsafeAtomicAdd.
//  - LDS 76KB (XB 64K + WT 8K + QB 8x512B).
//  - P3 attn + epilogue stores direct from MFMA regs; nt on attn stores.

typedef __bf16 bf16x8 __attribute__((ext_vector_type(8)));
typedef float  f32x4  __attribute__((ext_vector_type(4)));
typedef unsigned int u32;
typedef u32 u32x4 __attribute__((ext_vector_type(4)));

#define XB_OFF  0         // 65536: X bf16 — XRM (row-major, swizzled) during
                          //        Q/S phase, then XCM (col-major) during P3
#define WT_OFF  65536     // 8192 : W^T [e][d], stride 128, cell XOR (d>>3)^(e&7)
#define QB_OFF  73728     // 8*512: per-wave Q quarter-bounce (16 rows x 32B)
#define LDS_BYTES 77824

static __device__ __forceinline__ u32 f2bf(float f) {
    u32 u = __builtin_bit_cast(u32, f);
    u += 0x7fffu + ((u >> 16) & 1u);   // RNE (finite)
    return u >> 16;
}
static __device__ __forceinline__ float bflo2f(u32 p) { return __builtin_bit_cast(float, p << 16); }
static __device__ __forceinline__ float bfhi2f(u32 p) { return __builtin_bit_cast(float, p & 0xffff0000u); }

__global__ __launch_bounds__(512, 2) void convattn_kernel(
    const float* __restrict__ inp,   // [16,512,4,64]
    const float* __restrict__ Wg,    // [4,4,64,64]
    float* __restrict__ out)         // out0 (2097152, pre-zeroed) ++ attn (67108864)
{
    extern __shared__ __align__(16) char smem[];
    const int tid  = threadIdx.x;
    const int wave = tid >> 6;
    const int lane = tid & 63;
    const int g    = lane >> 4;     // MFMA k-group
    const int ln   = lane & 15;     // MFMA row/col within tile

    const int bid = blockIdx.x;
    const int b  = bid & 15;        // bid%8 = b%8: same-b blocks share an XCD
    const int o  = (bid >> 4) & 3;
    const int lt = (bid >> 6) & 3;  // 0..3: 128 l's per block
    const int jh = bid >> 8;        // 0..1: j in {2jh, 2jh+1}
    const int l0 = lt * 128 + wave * 16;   // this wave's 16 l-columns

    float* attn_out = out + (size_t)2097152;
    char* qb = smem + QB_OFF + wave * 512;   // wave-private Q quarter-bounce

    const int sq = tid & 15;   // staging e-quad (e0 = sq*4)
    const int sp = tid >> 4;   // 0..31

    f32x4 acc_c[4];
    #pragma unroll
    for (int i = 0; i < 4; ++i) { f32x4 z = {0.f,0.f,0.f,0.f}; acc_c[i] = z; }

    #pragma unroll 1
    for (int jj = 0; jj < 2; ++jj) {
        const int j = jh * 2 + jj;
        __syncthreads();   // guard XB/WT reuse across j

        // ---------------- stage XRM (X row-major bf16, swizzled) + W^T ----------------
        {
            const int e0 = sq << 2;
            #pragma unroll
            for (int it = 0; it < 8; ++it) {
                const int m0 = it * 64 + sp * 2;
                const float* src = inp + (((size_t)b * 512 + m0) * 4 + j) * 64 + e0;
                const float4 va = *(const float4*)src;
                const float4 vb = *(const float4*)(src + 256);   // row m0+1
                uint2 w0; w0.x = f2bf(va.x) | (f2bf(va.y) << 16); w0.y = f2bf(va.z) | (f2bf(va.w) << 16);
                *(uint2*)(smem + XB_OFF + m0 * 128 + (((sq >> 1) ^ (m0 & 7)) * 16) + ((sq & 1) * 8)) = w0;
                uint2 w1; w1.x = f2bf(vb.x) | (f2bf(vb.y) << 16); w1.y = f2bf(vb.z) | (f2bf(vb.w) << 16);
                *(uint2*)(smem + XB_OFF + (m0 + 1) * 128 + (((sq >> 1) ^ ((m0 + 1) & 7)) * 16) + ((sq & 1) * 8)) = w1;
            }
            // W^T: thread -> W row d = tid>>3, e-range (tid&7)*8 .. +7
            const int wd = tid >> 3;
            const int we = (tid & 7) << 3;
            const float* wsrc = Wg + (((size_t)o * 4 + j) * 64 + wd) * 64 + we;
            #pragma unroll
            for (int c = 0; c < 2; ++c) {
                const float4 wv = *(const float4*)(wsrc + c * 4);
                const int e = we + c * 4;
                const u32 q0 = f2bf(wv.x), q1 = f2bf(wv.y), q2 = f2bf(wv.z), q3 = f2bf(wv.w);
                *(unsigned short*)(smem + WT_OFF + (e + 0) * 128 + (((wd >> 3) ^ ((e + 0) & 7)) * 16) + ((wd & 7) * 2)) = (unsigned short)q0;
                *(unsigned short*)(smem + WT_OFF + (e + 1) * 128 + (((wd >> 3) ^ ((e + 1) & 7)) * 16) + ((wd & 7) * 2)) = (unsigned short)q1;
                *(unsigned short*)(smem + WT_OFF + (e + 2) * 128 + (((wd >> 3) ^ ((e + 2) & 7)) * 16) + ((wd & 7) * 2)) = (unsigned short)q2;
                *(unsigned short*)(smem + WT_OFF + (e + 3) * 128 + (((wd >> 3) ^ ((e + 3) & 7)) * 16) + ((wd & 7) * 2)) = (unsigned short)q3;
            }
        }
        __syncthreads();

        // ---------------- Q for this wave's 16 l's; 4 quarter-bounces -> Q^T B-frags ----------------
        bf16x8 bq0, bq1;
        {
            const int lq = l0 + ln;
            const bf16x8 aq0 = *(const bf16x8*)(smem + XB_OFF + lq * 128 + ((g ^ (lq & 7)) * 16));
            const bf16x8 aq1 = *(const bf16x8*)(smem + XB_OFF + lq * 128 + (((4 + g) ^ (lq & 7)) * 16));
            bf16x8 rd[4];
            #pragma unroll
            for (int h = 0; h < 4; ++h) {
                const int e = h * 16 + ln;
                const bf16x8 bw0 = *(const bf16x8*)(smem + WT_OFF + e * 128 + ((g ^ (e & 7)) * 16));
                const bf16x8 bw1 = *(const bf16x8*)(smem + WT_OFF + e * 128 + (((4 + g) ^ (e & 7)) * 16));
                f32x4 t = {0.f,0.f,0.f,0.f};
                t = __builtin_amdgcn_mfma_f32_16x16x32_bf16(aq0, bw0, t, 0, 0, 0);
                t = __builtin_amdgcn_mfma_f32_16x16x32_bf16(aq1, bw1, t, 0, 0, 0);
                // bounce tile: row = l_local = g*4+r, col = e_local = ln (16 rows x 32B)
                #pragma unroll
                for (int r = 0; r < 4; ++r)
                    *(unsigned short*)(qb + (g * 4 + r) * 32 + ln * 2) = (unsigned short)f2bf(t[r]);
                rd[h] = *(const bf16x8*)(qb + ln * 32 + (g & 1) * 16);
                __builtin_amdgcn_sched_barrier(0);  // keep next h's writes after this read
            }
            bq0 = (g < 2) ? rd[0] : rd[1];   // lane's bq0 = e g*8..+7 -> h = g>>1
            bq1 = (g < 2) ? rd[2] : rd[3];
        }

        // ---------------- S phase: S^T = X * Q^T, exp (no max pass), stash bf16 E ----------------
        float sum = 0.f;
        u32 sLo[32], sHi[32];
        #pragma unroll
        for (int mt = 0; mt < 32; ++mt) {
            const int m = mt * 16 + ln;
            const bf16x8 ax0 = *(const bf16x8*)(smem + XB_OFF + m * 128 + ((g ^ (m & 7)) * 16));
            const bf16x8 ax1 = *(const bf16x8*)(smem + XB_OFF + m * 128 + (((4 + g) ^ (m & 7)) * 16));
            f32x4 t = {0.f,0.f,0.f,0.f};
            t = __builtin_amdgcn_mfma_f32_16x16x32_bf16(ax0, bq0, t, 0, 0, 0);
            t = __builtin_amdgcn_mfma_f32_16x16x32_bf16(ax1, bq1, t, 0, 0, 0);
            const float e0v = __expf(t[0] * 0.125f);   // |S/8| <= ~6.5: fp32-safe
            const float e1v = __expf(t[1] * 0.125f);
            const float e2v = __expf(t[2] * 0.125f);
            const float e3v = __expf(t[3] * 0.125f);
            sum += (e0v + e1v) + (e2v + e3v);
            sLo[mt] = f2bf(e0v) | (f2bf(e1v) << 16);
            sHi[mt] = f2bf(e2v) | (f2bf(e3v) << 16);
        }
        sum += __shfl_xor(sum, 16, 64);
        sum += __shfl_xor(sum, 32, 64);
        const float inv = 1.0f / sum;

        __syncthreads();   // all waves done reading XRM

        // ---------------- restage XB as XCM (X col-major bf16, swizzled; L2-hot) ----------------
        {
            const int e0 = sq << 2;
            #pragma unroll
            for (int it = 0; it < 8; ++it) {
                const int m0 = it * 64 + sp * 2;
                const float* src = inp + (((size_t)b * 512 + m0) * 4 + j) * 64 + e0;
                const float4 va = *(const float4*)src;
                const float4 vb = *(const float4*)(src + 256);
                const u32 p0 = f2bf(va.x) | (f2bf(vb.x) << 16);
                const u32 p1 = f2bf(va.y) | (f2bf(vb.y) << 16);
                const u32 p2 = f2bf(va.z) | (f2bf(vb.z) << 16);
                const u32 p3v = f2bf(va.w) | (f2bf(vb.w) << 16);
                const u32 pc[4] = {p0, p1, p2, p3v};
                #pragma unroll
                for (int c = 0; c < 4; ++c) {
                    const int d = e0 + c;
                    *(u32*)(smem + XB_OFF + d * 1024 + (((m0 >> 3) ^ ((d >> 2) & 7)) * 16) + ((m0 & 7) * 2)) = pc[c];
                }
            }
        }
        __syncthreads();

        // ---------------- P3: direct attn stores + ctx^T += X^T * E^T ----------------
        // Lane (ln,g) holds E^T[m = mt*16+g*4+r][l = l0+ln]: 4 consecutive m for one l
        // -> direct f32x4 store; address set identical to the old LDS bounce.
        const size_t abase = ((size_t)((o * 4 + j) * 16 + b)) * 262144 + (size_t)(l0 + ln) * 512;
        const int srcLo = ((g & 1) << 5) + ln;
        const int srcHi = srcLo + 16;
        #pragma unroll
        for (int ch = 0; ch < 16; ++ch) {
            u32 pLo[2], pHi[2];
            #pragma unroll
            for (int s = 0; s < 2; ++s) {
                const int mt = ch * 2 + s;
                const float a0v = bflo2f(sLo[mt]) * inv;
                const float a1v = bfhi2f(sLo[mt]) * inv;
                const float a2v = bflo2f(sHi[mt]) * inv;
                const float a3v = bfhi2f(sHi[mt]) * inv;
                const f32x4 av = {a0v, a1v, a2v, a3v};
                __builtin_nontemporal_store(av,
                    (f32x4*)(attn_out + abase + mt * 16 + g * 4));
                pLo[s] = f2bf(a0v) | (f2bf(a1v) << 16);
                pHi[s] = f2bf(a2v) | (f2bf(a3v) << 16);
            }
            // E^T B-frag via cross-lane (g-only moves: same column stays in same ln)
            const u32 a0s = (u32)__shfl((int)pLo[0], srcLo, 64);
            const u32 a1s = (u32)__shfl((int)pHi[0], srcLo, 64);
            const u32 a2s = (u32)__shfl((int)pLo[0], srcHi, 64);
            const u32 a3s = (u32)__shfl((int)pHi[0], srcHi, 64);
            const u32 b0s = (u32)__shfl((int)pLo[1], srcLo, 64);
            const u32 b1s = (u32)__shfl((int)pHi[1], srcLo, 64);
            const u32 b2s = (u32)__shfl((int)pLo[1], srcHi, 64);
            const u32 b3s = (u32)__shfl((int)pHi[1], srcHi, 64);
            const bool hi = (g >= 2);
            const u32 dw0 = hi ? b0s : a0s;
            const u32 dw1 = hi ? b1s : a1s;
            const u32 dw2 = hi ? b2s : a2s;
            const u32 dw3 = hi ? b3s : a3s;
            const bf16x8 bfrag = __builtin_bit_cast(bf16x8, (u32x4){dw0, dw1, dw2, dw3});
            #pragma unroll
            for (int dt = 0; dt < 4; ++dt) {
                const int d = dt * 16 + ln;
                const bf16x8 ax = *(const bf16x8*)(smem + XB_OFF + d * 1024 +
                                   (((ch * 4 + g) ^ ((d >> 2) & 7)) * 16));
                acc_c[dt] = __builtin_amdgcn_mfma_f32_16x16x32_bf16(ax, bfrag, acc_c[dt], 0, 0, 0);
            }
        }
    }

    // ---------------- epilogue: out[b,l,o,d] += 0.25 * ctx_partial (2-way j-split) ----------------
    // Lane (ln,g) holds ctx^T[d = dt*16+g*4+r][l = l0+ln]: 4 consecutive d for one l.
    float* obase = out + (((size_t)b * 512 + (l0 + ln)) * 4 + o) * 64;
    #pragma unroll
    for (int dt = 0; dt < 4; ++dt) {
        #pragma unroll
        for (int r = 0; r < 4; ++r)
            unsafeAtomicAdd(obase + dt * 16 + g * 4 + r, acc_c[dt][r] * 0.25f);
    }
}

extern "C" void kernel_launch(void* const* d_in, const int* in_sizes, int n_in,
                              void* d_out, int out_size, void* d_ws, size_t ws_size,
                              hipStream_t stream) {
    const float* inp = (const float*)d_in[0];
    const float* Wg  = (const float*)d_in[1];
    float* out = (float*)d_out;
    (void)hipMemsetAsync(d_out, 0, (size_t)2097152 * sizeof(float), stream);  // out0 only
    (void)hipFuncSetAttribute((const void*)convattn_kernel,
                              hipFuncAttributeMaxDynamicSharedMemorySize, LDS_BYTES);
    convattn_kernel<<<dim3(512), dim3(512), LDS_BYTES, stream>>>(inp, Wg, out);
}

// Round 6
// 390.787 us; speedup vs baseline: 1.2965x; 1.0075x over previous
//
#include <hip/hip_runtime.h>
#include <stdint.h>

// ConvAttnLayer: B=16, L=512, J=4, O=4, D=E=64.
// out0 = mean_j softmax(X_j W_oj X_j^T / 8) X_j ; out1 = attn (268 MB fp32).
//
// Round-7: attack the write stream (round-5 post-mortem: FETCH now ideal
// 21 MB, spill gone, but WRITE=475 MB vs 277 ideal = 1.71x amplification,
// stream at 2.7 TB/s). Every prior attn store issued 16-row x 64B
// (half-line) wave footprints; with nt (no L2 merge) each half-line pays
// line-granule cost at DRAM. Fix: per-wave 2KB LDS bounce per ch-tile
// (16 rows x 32 f32, XOR-swizzled, 2x ds_write_b128 + 2x ds_read_b128),
// then 2 nt stores of 8 rows x full 128B lines each. Single change vs
// round-5; everything else frozen.
//  - lb(512,2): VGPR=128 spill-free (round-5 verified). 1 block/CU
//    (arch+acc > 128-reg tier blocks a 2nd block; accepted).
//  - j-split: 512 blocks x 512 thr; j in {2jh, 2jh+1}; out0 via memset +
//    2-way unsafeAtomicAdd.
//  - LDS 88K: XB 64K + WT 8K + AB 8x2KB (Q bounce aliases AB).

typedef __bf16 bf16x8 __attribute__((ext_vector_type(8)));
typedef float  f32x4  __attribute__((ext_vector_type(4)));
typedef unsigned int u32;
typedef u32 u32x4 __attribute__((ext_vector_type(4)));

#define XB_OFF  0         // 65536: X bf16 — XRM (row-major, swizzled) during
                          //        Q/S phase, then XCM (col-major) during P3
#define WT_OFF  65536     // 8192 : W^T [e][d], stride 128, cell XOR (d>>3)^(e&7)
#define AB_OFF  73728     // 8*2048: per-wave attn bounce (16 rows x 128B, swizzled);
                          //         Q quarter-bounce aliases the first 512B
#define LDS_BYTES 90112

static __device__ __forceinline__ u32 f2bf(float f) {
    u32 u = __builtin_bit_cast(u32, f);
    u += 0x7fffu + ((u >> 16) & 1u);   // RNE (finite)
    return u >> 16;
}
static __device__ __forceinline__ float bflo2f(u32 p) { return __builtin_bit_cast(float, p << 16); }
static __device__ __forceinline__ float bfhi2f(u32 p) { return __builtin_bit_cast(float, p & 0xffff0000u); }

__global__ __launch_bounds__(512, 2) void convattn_kernel(
    const float* __restrict__ inp,   // [16,512,4,64]
    const float* __restrict__ Wg,    // [4,4,64,64]
    float* __restrict__ out)         // out0 (2097152, pre-zeroed) ++ attn (67108864)
{
    extern __shared__ __align__(16) char smem[];
    const int tid  = threadIdx.x;
    const int wave = tid >> 6;
    const int lane = tid & 63;
    const int g    = lane >> 4;     // MFMA k-group
    const int ln   = lane & 15;     // MFMA row/col within tile
    const int row0 = lane >> 3;     // bounce-read row (0..7)
    const int cl   = lane & 7;      // bounce-read 16B-chunk within line

    const int bid = blockIdx.x;
    const int b  = bid & 15;        // bid%8 = b%8: same-b blocks share an XCD
    const int o  = (bid >> 4) & 3;
    const int lt = (bid >> 6) & 3;  // 0..3: 128 l's per block
    const int jh = bid >> 8;        // 0..1: j in {2jh, 2jh+1}
    const int l0 = lt * 128 + wave * 16;   // this wave's 16 l-columns

    float* attn_out = out + (size_t)2097152;
    char* ab = smem + AB_OFF + wave * 2048;  // wave-private attn bounce
    char* qb = ab;                           // Q quarter-bounce aliases (different time)

    const int sq = tid & 15;   // staging e-quad (e0 = sq*4)
    const int sp = tid >> 4;   // 0..31

    f32x4 acc_c[4];
    #pragma unroll
    for (int i = 0; i < 4; ++i) { f32x4 z = {0.f,0.f,0.f,0.f}; acc_c[i] = z; }

    #pragma unroll 1
    for (int jj = 0; jj < 2; ++jj) {
        const int j = jh * 2 + jj;
        __syncthreads();   // guard XB/WT reuse across j

        // ---------------- stage XRM (X row-major bf16, swizzled) + W^T ----------------
        {
            const int e0 = sq << 2;
            #pragma unroll
            for (int it = 0; it < 8; ++it) {
                const int m0 = it * 64 + sp * 2;
                const float* src = inp + (((size_t)b * 512 + m0) * 4 + j) * 64 + e0;
                const float4 va = *(const float4*)src;
                const float4 vb = *(const float4*)(src + 256);   // row m0+1
                uint2 w0; w0.x = f2bf(va.x) | (f2bf(va.y) << 16); w0.y = f2bf(va.z) | (f2bf(va.w) << 16);
                *(uint2*)(smem + XB_OFF + m0 * 128 + (((sq >> 1) ^ (m0 & 7)) * 16) + ((sq & 1) * 8)) = w0;
                uint2 w1; w1.x = f2bf(vb.x) | (f2bf(vb.y) << 16); w1.y = f2bf(vb.z) | (f2bf(vb.w) << 16);
                *(uint2*)(smem + XB_OFF + (m0 + 1) * 128 + (((sq >> 1) ^ ((m0 + 1) & 7)) * 16) + ((sq & 1) * 8)) = w1;
            }
            // W^T: thread -> W row d = tid>>3, e-range (tid&7)*8 .. +7
            const int wd = tid >> 3;
            const int we = (tid & 7) << 3;
            const float* wsrc = Wg + (((size_t)o * 4 + j) * 64 + wd) * 64 + we;
            #pragma unroll
            for (int c = 0; c < 2; ++c) {
                const float4 wv = *(const float4*)(wsrc + c * 4);
                const int e = we + c * 4;
                const u32 q0 = f2bf(wv.x), q1 = f2bf(wv.y), q2 = f2bf(wv.z), q3 = f2bf(wv.w);
                *(unsigned short*)(smem + WT_OFF + (e + 0) * 128 + (((wd >> 3) ^ ((e + 0) & 7)) * 16) + ((wd & 7) * 2)) = (unsigned short)q0;
                *(unsigned short*)(smem + WT_OFF + (e + 1) * 128 + (((wd >> 3) ^ ((e + 1) & 7)) * 16) + ((wd & 7) * 2)) = (unsigned short)q1;
                *(unsigned short*)(smem + WT_OFF + (e + 2) * 128 + (((wd >> 3) ^ ((e + 2) & 7)) * 16) + ((wd & 7) * 2)) = (unsigned short)q2;
                *(unsigned short*)(smem + WT_OFF + (e + 3) * 128 + (((wd >> 3) ^ ((e + 3) & 7)) * 16) + ((wd & 7) * 2)) = (unsigned short)q3;
            }
        }
        __syncthreads();

        // ---------------- Q for this wave's 16 l's; 4 quarter-bounces -> Q^T B-frags ----------------
        bf16x8 bq0, bq1;
        {
            const int lq = l0 + ln;
            const bf16x8 aq0 = *(const bf16x8*)(smem + XB_OFF + lq * 128 + ((g ^ (lq & 7)) * 16));
            const bf16x8 aq1 = *(const bf16x8*)(smem + XB_OFF + lq * 128 + (((4 + g) ^ (lq & 7)) * 16));
            bf16x8 rd[4];
            #pragma unroll
            for (int h = 0; h < 4; ++h) {
                const int e = h * 16 + ln;
                const bf16x8 bw0 = *(const bf16x8*)(smem + WT_OFF + e * 128 + ((g ^ (e & 7)) * 16));
                const bf16x8 bw1 = *(const bf16x8*)(smem + WT_OFF + e * 128 + (((4 + g) ^ (e & 7)) * 16));
                f32x4 t = {0.f,0.f,0.f,0.f};
                t = __builtin_amdgcn_mfma_f32_16x16x32_bf16(aq0, bw0, t, 0, 0, 0);
                t = __builtin_amdgcn_mfma_f32_16x16x32_bf16(aq1, bw1, t, 0, 0, 0);
                // bounce tile: row = l_local = g*4+r, col = e_local = ln (16 rows x 32B)
                #pragma unroll
                for (int r = 0; r < 4; ++r)
                    *(unsigned short*)(qb + (g * 4 + r) * 32 + ln * 2) = (unsigned short)f2bf(t[r]);
                rd[h] = *(const bf16x8*)(qb + ln * 32 + (g & 1) * 16);
                __builtin_amdgcn_sched_barrier(0);  // keep next h's writes after this read
            }
            bq0 = (g < 2) ? rd[0] : rd[1];   // lane's bq0 = e g*8..+7 -> h = g>>1
            bq1 = (g < 2) ? rd[2] : rd[3];
        }

        // ---------------- S phase: S^T = X * Q^T, exp (no max pass), stash bf16 E ----------------
        float sum = 0.f;
        u32 sLo[32], sHi[32];
        #pragma unroll
        for (int mt = 0; mt < 32; ++mt) {
            const int m = mt * 16 + ln;
            const bf16x8 ax0 = *(const bf16x8*)(smem + XB_OFF + m * 128 + ((g ^ (m & 7)) * 16));
            const bf16x8 ax1 = *(const bf16x8*)(smem + XB_OFF + m * 128 + (((4 + g) ^ (m & 7)) * 16));
            f32x4 t = {0.f,0.f,0.f,0.f};
            t = __builtin_amdgcn_mfma_f32_16x16x32_bf16(ax0, bq0, t, 0, 0, 0);
            t = __builtin_amdgcn_mfma_f32_16x16x32_bf16(ax1, bq1, t, 0, 0, 0);
            const float e0v = __expf(t[0] * 0.125f);   // |S/8| <= ~6.5: fp32-safe
            const float e1v = __expf(t[1] * 0.125f);
            const float e2v = __expf(t[2] * 0.125f);
            const float e3v = __expf(t[3] * 0.125f);
            sum += (e0v + e1v) + (e2v + e3v);
            sLo[mt] = f2bf(e0v) | (f2bf(e1v) << 16);
            sHi[mt] = f2bf(e2v) | (f2bf(e3v) << 16);
        }
        sum += __shfl_xor(sum, 16, 64);
        sum += __shfl_xor(sum, 32, 64);
        const float inv = 1.0f / sum;

        __syncthreads();   // all waves done reading XRM

        // ---------------- restage XB as XCM (X col-major bf16, swizzled; L2-hot) ----------------
        {
            const int e0 = sq << 2;
            #pragma unroll
            for (int it = 0; it < 8; ++it) {
                const int m0 = it * 64 + sp * 2;
                const float* src = inp + (((size_t)b * 512 + m0) * 4 + j) * 64 + e0;
                const float4 va = *(const float4*)src;
                const float4 vb = *(const float4*)(src + 256);
                const u32 p0 = f2bf(va.x) | (f2bf(vb.x) << 16);
                const u32 p1 = f2bf(va.y) | (f2bf(vb.y) << 16);
                const u32 p2 = f2bf(va.z) | (f2bf(vb.z) << 16);
                const u32 p3v = f2bf(va.w) | (f2bf(vb.w) << 16);
                const u32 pc[4] = {p0, p1, p2, p3v};
                #pragma unroll
                for (int c = 0; c < 4; ++c) {
                    const int d = e0 + c;
                    *(u32*)(smem + XB_OFF + d * 1024 + (((m0 >> 3) ^ ((d >> 2) & 7)) * 16) + ((m0 & 7) * 2)) = pc[c];
                }
            }
        }
        __syncthreads();

        // ---------------- P3: full-line attn stores (2KB bounce) + ctx^T += X^T * E^T ----------------
        // Lane (ln,g) holds E^T[m = mt*16+g*4+r][l = l0+ln]. Per ch: stage the
        // 16l x 32m f32 tile into ab (XOR-swizzled), then store 8 rows x 128B
        // FULL lines per instruction (2 instructions cover the tile).
        const size_t abase_w = ((size_t)((o * 4 + j) * 16 + b)) * 262144 + (size_t)l0 * 512;
        const int srcLo = ((g & 1) << 5) + ln;
        const int srcHi = srcLo + 16;
        #pragma unroll
        for (int ch = 0; ch < 16; ++ch) {
            u32 pLo[2], pHi[2];
            #pragma unroll
            for (int s = 0; s < 2; ++s) {
                const int mt = ch * 2 + s;
                const float a0v = bflo2f(sLo[mt]) * inv;
                const float a1v = bfhi2f(sLo[mt]) * inv;
                const float a2v = bflo2f(sHi[mt]) * inv;
                const float a3v = bfhi2f(sHi[mt]) * inv;
                const f32x4 av = {a0v, a1v, a2v, a3v};
                // bounce write: row=ln, col words s*16+g*4 .. +3, XOR (ln&7)*4
                *(f32x4*)(ab + ln * 128 + (((s * 16 + g * 4) ^ ((ln & 7) * 4)) * 4)) = av;
                pLo[s] = f2bf(a0v) | (f2bf(a1v) << 16);
                pHi[s] = f2bf(a2v) | (f2bf(a3v) << 16);
            }
            // read back 8 rows x 128B per instruction, nt-store full lines
            #pragma unroll
            for (int k = 0; k < 2; ++k) {
                const int row = k * 8 + row0;
                const f32x4 rv = *(const f32x4*)(ab + row * 128 + (((cl * 4) ^ ((row & 7) * 4)) * 4));
                __builtin_nontemporal_store(rv,
                    (f32x4*)(attn_out + abase_w + (size_t)row * 512 + ch * 32 + cl * 4));
            }
            __builtin_amdgcn_sched_barrier(0);  // reads precede next ch's writes
            // E^T B-frag via cross-lane (g-only moves: same column stays in same ln)
            const u32 a0s = (u32)__shfl((int)pLo[0], srcLo, 64);
            const u32 a1s = (u32)__shfl((int)pHi[0], srcLo, 64);
            const u32 a2s = (u32)__shfl((int)pLo[0], srcHi, 64);
            const u32 a3s = (u32)__shfl((int)pHi[0], srcHi, 64);
            const u32 b0s = (u32)__shfl((int)pLo[1], srcLo, 64);
            const u32 b1s = (u32)__shfl((int)pHi[1], srcLo, 64);
            const u32 b2s = (u32)__shfl((int)pLo[1], srcHi, 64);
            const u32 b3s = (u32)__shfl((int)pHi[1], srcHi, 64);
            const bool hi = (g >= 2);
            const u32 dw0 = hi ? b0s : a0s;
            const u32 dw1 = hi ? b1s : a1s;
            const u32 dw2 = hi ? b2s : a2s;
            const u32 dw3 = hi ? b3s : a3s;
            const bf16x8 bfrag = __builtin_bit_cast(bf16x8, (u32x4){dw0, dw1, dw2, dw3});
            #pragma unroll
            for (int dt = 0; dt < 4; ++dt) {
                const int d = dt * 16 + ln;
                const bf16x8 ax = *(const bf16x8*)(smem + XB_OFF + d * 1024 +
                                   (((ch * 4 + g) ^ ((d >> 2) & 7)) * 16));
                acc_c[dt] = __builtin_amdgcn_mfma_f32_16x16x32_bf16(ax, bfrag, acc_c[dt], 0, 0, 0);
            }
        }
    }

    // ---------------- epilogue: out[b,l,o,d] += 0.25 * ctx_partial (2-way j-split) ----------------
    // Lane (ln,g) holds ctx^T[d = dt*16+g*4+r][l = l0+ln]: 4 consecutive d for one l.
    float* obase = out + (((size_t)b * 512 + (l0 + ln)) * 4 + o) * 64;
    #pragma unroll
    for (int dt = 0; dt < 4; ++dt) {
        #pragma unroll
        for (int r = 0; r < 4; ++r)
            unsafeAtomicAdd(obase + dt * 16 + g * 4 + r, acc_c[dt][r] * 0.25f);
    }
}

extern "C" void kernel_launch(void* const* d_in, const int* in_sizes, int n_in,
                              void* d_out, int out_size, void* d_ws, size_t ws_size,
                              hipStream_t stream) {
    const float* inp = (const float*)d_in[0];
    const float* Wg  = (const float*)d_in[1];
    float* out = (float*)d_out;
    (void)hipMemsetAsync(d_out, 0, (size_t)2097152 * sizeof(float), stream);  // out0 only
    (void)hipFuncSetAttribute((const void*)convattn_kernel,
                              hipFuncAttributeMaxDynamicSharedMemorySize, LDS_BYTES);
    convattn_kernel<<<dim3(512), dim3(512), LDS_BYTES, stream>>>(inp, Wg, out);
}